// Round 6
// baseline (88.098 us; speedup 1.0000x reference)
//
#include <hip/hip_runtime.h>
#include <math.h>

#define B_  16
#define F_  64
#define C_  64
#define M_  512
#define OC_ 32

// ---------------------------------------------------------------------------
// k1: s[b,c,m] = mean_f x[b,f,c,m], m-split 4-ways for occupancy.
// (unchanged from R3 — best known)
// ---------------------------------------------------------------------------
__global__ __launch_bounds__(128, 6) void k1_mean(
    const float* __restrict__ x,
    float* __restrict__ s_out, float* __restrict__ rpart)
{
    const int gid = blockIdx.x;        // bc*4 + q
    const int q   = gid & 3;
    const int bc  = gid >> 2;
    const int b   = bc >> 6;
    const int c   = bc & 63;
    const int t   = threadIdx.x;
    const int tf  = t >> 5;            // 0..3 -> f chunk
    const int tm  = t & 31;            // float4 column within window
    const int m4  = (q << 5) + tm;     // global float4 index 0..127

    const size_t rowbase = ((size_t)b * F_ * C_ + c) * M_;   // + f*C*M
    float ax = 0.f, ay = 0.f, az = 0.f, aw = 0.f;
    #pragma unroll 8
    for (int j = 0; j < 16; ++j) {
        const int f = (tf << 4) + j;
        const float4 v = ((const float4*)(x + rowbase + (size_t)f * C_ * M_))[m4];
        ax += v.x; ay += v.y; az += v.z; aw += v.w;
    }

    __shared__ float4 red[4][32];
    red[tf][tm] = make_float4(ax, ay, az, aw);
    __syncthreads();

    if (tf == 0) {                     // lanes 0..31 of wave 0
        const float4 r1 = red[1][tm], r2 = red[2][tm], r3 = red[3][tm];
        const float inv_f = 1.0f / (float)F_;
        float4 sv;
        sv.x = (ax + r1.x + r2.x + r3.x) * inv_f;
        sv.y = (ay + r1.y + r2.y + r3.y) * inv_f;
        sv.z = (az + r1.z + r2.z + r3.z) * inv_f;
        sv.w = (aw + r1.w + r2.w + r3.w) * inv_f;
        ((float4*)(s_out + (size_t)bc * M_))[m4] = sv;

        float p = sv.x + sv.y + sv.z + sv.w;
        #pragma unroll
        for (int off = 16; off > 0; off >>= 1) p += __shfl_xor(p, off);
        if (t == 0) rpart[gid] = p;
    }
}

// ---------------------------------------------------------------------------
// k2 v3-diag: identical math to R3's k2, but the stage+reduce pass runs
// nreps times (host passes nreps=3, opaque0=0). Each pass recomputes
// bit-identical redD/redA, so the output is unchanged and deterministic.
// rep*opaque0 in the address defeats LICM/CSE so A is truly re-read.
// Purpose: (a) surface k2 in rocprof top-5, (b) Δdur vs R3 separates
// fetch-side cost (passes 2-3 are L2-hot -> small Δ) from issue/compute
// cost (Δ ~ full pass).
// ---------------------------------------------------------------------------
__global__ __launch_bounds__(256) void k2_laplace(
    const float* __restrict__ A, const float* __restrict__ phys,
    const float* __restrict__ kappa_p, const float* __restrict__ alpha_p,
    const float* __restrict__ s_in, const float* __restrict__ rpart,
    const float* __restrict__ w1, const float* __restrict__ b1,
    const float* __restrict__ w2, const float* __restrict__ b2,
    float* __restrict__ snew, int nreps, int opaque0)
{
    __shared__ float Al[C_ * 65];
    __shared__ float sl[C_];
    __shared__ float redD[4 * C_];
    __shared__ float redA[4 * C_];

    const int bm = blockIdx.x;     // b*M + m
    const int b  = bm >> 9;
    const int m  = bm & 511;
    const int t  = threadIdx.x;    // 0..255
    const int c  = t & 63;
    const int q  = t >> 6;

    // r-MLP preamble + s gather (once)
    float r = 0.f;
    if (t < 64) {
        const float4 rp = ((const float4*)rpart)[b * C_ + t];
        const float rin = (rp.x + rp.y + rp.z + rp.w) * (1.0f / (float)M_);
        r = b2[0];
        #pragma unroll
        for (int j = 0; j < 16; ++j) {
            float h = rin * w1[j] + b1[j];        // w1 is (16,1)
            h = (h > 0.f) ? h : (expf(h) - 1.f);  // ELU(alpha=1)
            r += h * w2[j];
        }
        sl[t] = s_in[((size_t)b * C_ + t) * M_ + m];
    }

    const float4* Ap = (const float4*)(A + (size_t)bm * (C_ * C_));

    for (int rep = 0; rep < nreps; ++rep) {
        // stage A[b,m,:,:] (4096 f32), pad stride 65
        #pragma unroll
        for (int i = 0; i < 4; ++i) {
            const int idx = t + i * 256 + rep * opaque0;  // opaque0==0 at runtime
            const float4 v = Ap[idx];
            const int row = idx >> 4;          // 16 float4 per row
            const int col = (idx & 15) << 2;
            float* dst = &Al[row * 65 + col];
            dst[0] = v.x; dst[1] = v.y; dst[2] = v.z; dst[3] = v.w;
        }
        __syncthreads();

        // quarter-reductions: q selects 16 of the 64 summation indices
        float dpart = 0.f, apart = 0.f;
        const int j0 = q << 4;
        #pragma unroll
        for (int j = 0; j < 16; ++j) {
            dpart += Al[c * 65 + (j0 + j)];              // row c (deg)
            apart += Al[(j0 + j) * 65 + c] * sl[j0 + j]; // col c (A^T s)
        }
        redD[(q << 6) + c] = dpart;
        redA[(q << 6) + c] = apart;
        __syncthreads();   // also protects Al before next rep's staging
    }

    if (t < 64) {
        const float deg = redD[t] + redD[64 + t] + redD[128 + t] + redD[192 + t];
        const float As  = redA[t] + redA[64 + t] + redA[128 + t] + redA[192 + t];
        const float sval = sl[t];
        const float k    = log1pf(expf(kappa_p[0]));   // softplus
        const float Ls   = deg * sval - As;
        const float val  = sval - k * Ls
                         + (r + alpha_p[0] * phys[((size_t)b * C_ + t) * M_ + m]);
        snew[((size_t)b * C_ + t) * M_ + m] = val;
    }
}

// ---------------------------------------------------------------------------
// k3: out[b,o,c,m] = s_new[b,c,m]*pw[o] + pb[o]  (pure bandwidth, float4)
// ---------------------------------------------------------------------------
__global__ __launch_bounds__(256) void k3_expand(
    const float* __restrict__ snew,
    const float* __restrict__ pw, const float* __restrict__ pb,
    float* __restrict__ out)
{
    const int n4 = (B_ * OC_ * C_ * M_) / 4;   // 4,194,304
    for (int i = blockIdx.x * blockDim.x + threadIdx.x; i < n4;
         i += gridDim.x * blockDim.x) {
        const int m4 = i & 127;          // M/4 = 128
        const int c  = (i >> 7) & 63;
        const int o  = (i >> 13) & 31;
        const int b  = i >> 18;
        const float4 v = ((const float4*)snew)[(((b << 6) + c) << 7) + m4];
        const float w  = pw[o];
        const float bb = pb[o];
        float4 r;
        r.x = v.x * w + bb; r.y = v.y * w + bb;
        r.z = v.z * w + bb; r.w = v.w * w + bb;
        ((float4*)out)[i] = r;
    }
}

extern "C" void kernel_launch(void* const* d_in, const int* in_sizes, int n_in,
                              void* d_out, int out_size, void* d_ws, size_t ws_size,
                              hipStream_t stream)
{
    const float* x     = (const float*)d_in[0];
    const float* A     = (const float*)d_in[1];
    const float* phys  = (const float*)d_in[2];
    const float* kappa = (const float*)d_in[3];
    const float* alpha = (const float*)d_in[4];
    const float* w1    = (const float*)d_in[5];
    const float* b1    = (const float*)d_in[6];
    const float* w2    = (const float*)d_in[7];
    const float* b2    = (const float*)d_in[8];
    const float* pw    = (const float*)d_in[9];
    const float* pb    = (const float*)d_in[10];
    float* out = (float*)d_out;

    float* ws    = (float*)d_ws;
    float* s     = ws;                            // B*C*M
    float* snew  = ws + (size_t)B_ * C_ * M_;     // B*C*M
    float* rpart = ws + (size_t)2 * B_ * C_ * M_; // B*C*4 (16B-aligned)

    k1_mean<<<B_ * C_ * 4, 128, 0, stream>>>(x, s, rpart);
    k2_laplace<<<B_ * M_, 256, 0, stream>>>(A, phys, kappa, alpha, s, rpart,
                                            w1, b1, w2, b2, snew,
                                            /*nreps=*/3, /*opaque0=*/0);
    k3_expand<<<2048, 256, 0, stream>>>(snew, pw, pb, out);
}

// Round 7
// 77.189 us; speedup vs baseline: 1.1413x; 1.1413x over previous
//
#include <hip/hip_runtime.h>
#include <math.h>

#define B_  16
#define F_  64
#define C_  64
#define M_  512
#define OC_ 32

// ---------------------------------------------------------------------------
// k1: s[b,c,m] = mean_f x[b,f,c,m], m-split 4-ways for occupancy.
// (unchanged from R3 — best known)
// ---------------------------------------------------------------------------
__global__ __launch_bounds__(128, 6) void k1_mean(
    const float* __restrict__ x,
    float* __restrict__ s_out, float* __restrict__ rpart)
{
    const int gid = blockIdx.x;        // bc*4 + q
    const int q   = gid & 3;
    const int bc  = gid >> 2;
    const int b   = bc >> 6;
    const int c   = bc & 63;
    const int t   = threadIdx.x;
    const int tf  = t >> 5;            // 0..3 -> f chunk
    const int tm  = t & 31;            // float4 column within window
    const int m4  = (q << 5) + tm;     // global float4 index 0..127

    const size_t rowbase = ((size_t)b * F_ * C_ + c) * M_;   // + f*C*M
    float ax = 0.f, ay = 0.f, az = 0.f, aw = 0.f;
    #pragma unroll 8
    for (int j = 0; j < 16; ++j) {
        const int f = (tf << 4) + j;
        const float4 v = ((const float4*)(x + rowbase + (size_t)f * C_ * M_))[m4];
        ax += v.x; ay += v.y; az += v.z; aw += v.w;
    }

    __shared__ float4 red[4][32];
    red[tf][tm] = make_float4(ax, ay, az, aw);
    __syncthreads();

    if (tf == 0) {                     // lanes 0..31 of wave 0
        const float4 r1 = red[1][tm], r2 = red[2][tm], r3 = red[3][tm];
        const float inv_f = 1.0f / (float)F_;
        float4 sv;
        sv.x = (ax + r1.x + r2.x + r3.x) * inv_f;
        sv.y = (ay + r1.y + r2.y + r3.y) * inv_f;
        sv.z = (az + r1.z + r2.z + r3.z) * inv_f;
        sv.w = (aw + r1.w + r2.w + r3.w) * inv_f;
        ((float4*)(s_out + (size_t)bc * M_))[m4] = sv;

        float p = sv.x + sv.y + sv.z + sv.w;
        #pragma unroll
        for (int off = 16; off > 0; off >>= 1) p += __shfl_xor(p, off);
        if (t == 0) rpart[gid] = p;
    }
}

// ---------------------------------------------------------------------------
// k2 v5: persistent streaming. 512 blocks x 256 thr (all resident at
// 2 waves/SIMD). Each wave owns 4 consecutive m-tiles of one b; tiles
// flow through two NAMED register buffers (vA/vB) so the compiler emits
// counted vmcnt waits — one buffer's 16 loads always in flight while the
// other is reduced. No barriers in the stream (one prologue barrier).
// Reduction = R5's verified shuffle butterflies (lane l=(g,h): g=l>>4,
// h=l&15; v[j] = A[4j+g][4h..4h+3]; ends with deg,As for i=4h+g).
// s-broadcast via per-wave LDS strip (stride 5); sval/phys/snew are
// per-lane row-float4 (4 m per c in one 16B access).
// ---------------------------------------------------------------------------
struct DegAs { float deg, As; };

__device__ __forceinline__ DegAs reduce_tile(
    const float4 (&v)[16], const float* SLw, int mi, int g, int h)
{
    float d[16];
    float a0 = 0.f, a1 = 0.f, a2 = 0.f, a3 = 0.f;
    #pragma unroll
    for (int j = 0; j < 16; ++j) {
        const float sr = SLw[(4 * j + g) * 5 + mi];   // broadcast in h-group
        d[j] = v[j].x + v[j].y + v[j].z + v[j].w;
        a0 += sr * v[j].x; a1 += sr * v[j].y;
        a2 += sr * v[j].z; a3 += sr * v[j].w;
    }

    // deg reduce-scatter over h (keep j == h)
    float e[8];
    #pragma unroll
    for (int jj = 0; jj < 8; ++jj) {
        const float sd = (h & 8) ? d[jj] : d[jj + 8];
        const float rv = __shfl_xor(sd, 8);
        e[jj] = ((h & 8) ? d[jj + 8] : d[jj]) + rv;
    }
    float f2[4];
    #pragma unroll
    for (int jj = 0; jj < 4; ++jj) {
        const float sd = (h & 4) ? e[jj] : e[jj + 4];
        const float rv = __shfl_xor(sd, 4);
        f2[jj] = ((h & 4) ? e[jj + 4] : e[jj]) + rv;
    }
    float g2[2];
    #pragma unroll
    for (int jj = 0; jj < 2; ++jj) {
        const float sd = (h & 2) ? f2[jj] : f2[jj + 2];
        const float rv = __shfl_xor(sd, 2);
        g2[jj] = ((h & 2) ? f2[jj + 2] : f2[jj]) + rv;
    }
    float deg;
    {
        const float sd = (h & 1) ? g2[0] : g2[1];
        const float rv = __shfl_xor(sd, 1);
        deg = ((h & 1) ? g2[1] : g2[0]) + rv;      // deg of row 4h+g
    }

    // As reduce-scatter over g (keep k == g)
    const float send0 = (g & 1) ? a0 : a1;
    const float send1 = (g & 1) ? a2 : a3;
    const float r0 = __shfl_xor(send0, 16);
    const float r1 = __shfl_xor(send1, 16);
    const float b0v = ((g & 1) ? a1 : a0) + r0;
    const float b1v = ((g & 1) ? a3 : a2) + r1;
    const float send2 = (g & 2) ? b0v : b1v;
    const float r2 = __shfl_xor(send2, 32);
    const float Asv = ((g & 2) ? b1v : b0v) + r2;  // As of col 4h+g

    DegAs out; out.deg = deg; out.As = Asv;
    return out;
}

__global__ __launch_bounds__(256, 2) void k2_stream(
    const float* __restrict__ A, const float* __restrict__ phys,
    const float* __restrict__ kappa_p, const float* __restrict__ alpha_p,
    const float* __restrict__ s_in, const float* __restrict__ rpart,
    const float* __restrict__ w1, const float* __restrict__ b1,
    const float* __restrict__ w2, const float* __restrict__ b2,
    float* __restrict__ snew)
{
    __shared__ float SL[4 * C_ * 5];   // per-wave s strips, stride 5

    const int t  = threadIdx.x;
    const int w  = t >> 6;             // wave in block
    const int l  = t & 63;
    const int wg = blockIdx.x * 4 + w; // global wave 0..2047
    const int b  = wg >> 7;
    const int m0 = (wg & 127) << 2;    // 4-m strip
    const int g  = l >> 4;             // 0..3
    const int h  = l & 15;             // 0..15
    const int i  = 4 * h + g;          // output row this lane owns

    float* SLw = &SL[w * (C_ * 5)];

    // ---- prologue: s strip to LDS, per-lane row loads, r-MLP ----
    {
        const float4 sc = *(const float4*)(s_in + ((size_t)(b * C_ + l)) * M_ + m0);
        SLw[l * 5 + 0] = sc.x; SLw[l * 5 + 1] = sc.y;
        SLw[l * 5 + 2] = sc.z; SLw[l * 5 + 3] = sc.w;
    }
    const float4 sv4 = *(const float4*)(s_in + ((size_t)(b * C_ + i)) * M_ + m0);
    const float4 pv4 = *(const float4*)(phys + ((size_t)(b * C_ + i)) * M_ + m0);
    float r_i;
    {
        const float4 rp = ((const float4*)rpart)[b * C_ + l];
        const float rin = (rp.x + rp.y + rp.z + rp.w) * (1.0f / (float)M_);
        float r = b2[0];
        #pragma unroll
        for (int j = 0; j < 16; ++j) {
            float hh = rin * w1[j] + b1[j];
            hh = (hh > 0.f) ? hh : (expf(hh) - 1.f);   // ELU
            r += hh * w2[j];
        }
        r_i = __shfl(r, i, 64);        // pull r for row i from lane i
    }
    const float kk = log1pf(expf(kappa_p[0]));         // softplus(kappa)
    const float al = alpha_p[0];
    __syncthreads();                   // LDS strip visibility (once)

    // ---- streaming pipeline over 4 tiles, two named buffers ----
    const float* Abase = A + ((size_t)(b * M_ + m0)) * (C_ * C_);
    float4 vA[16], vB[16];
    #pragma unroll
    for (int j = 0; j < 16; ++j) vA[j] = ((const float4*)(Abase))[j * 64 + l];
    #pragma unroll
    for (int j = 0; j < 16; ++j) vB[j] = ((const float4*)(Abase + 4096))[j * 64 + l];

    const DegAs da0 = reduce_tile(vA, SLw, 0, g, h);   // waits vA only
    #pragma unroll
    for (int j = 0; j < 16; ++j) vA[j] = ((const float4*)(Abase + 8192))[j * 64 + l];
    const DegAs da1 = reduce_tile(vB, SLw, 1, g, h);
    #pragma unroll
    for (int j = 0; j < 16; ++j) vB[j] = ((const float4*)(Abase + 12288))[j * 64 + l];
    const DegAs da2 = reduce_tile(vA, SLw, 2, g, h);
    const DegAs da3 = reduce_tile(vB, SLw, 3, g, h);

    // ---- snew for row i, m0..m0+3 (one 16B store per lane) ----
    float4 ov;
    ov.x = sv4.x - kk * (da0.deg * sv4.x - da0.As) + (r_i + al * pv4.x);
    ov.y = sv4.y - kk * (da1.deg * sv4.y - da1.As) + (r_i + al * pv4.y);
    ov.z = sv4.z - kk * (da2.deg * sv4.z - da2.As) + (r_i + al * pv4.z);
    ov.w = sv4.w - kk * (da3.deg * sv4.w - da3.As) + (r_i + al * pv4.w);
    *(float4*)(snew + ((size_t)(b * C_ + i)) * M_ + m0) = ov;
}

// ---------------------------------------------------------------------------
// k3: out[b,o,c,m] = s_new[b,c,m]*pw[o] + pb[o]  (pure bandwidth, float4)
// ---------------------------------------------------------------------------
__global__ __launch_bounds__(256) void k3_expand(
    const float* __restrict__ snew,
    const float* __restrict__ pw, const float* __restrict__ pb,
    float* __restrict__ out)
{
    const int n4 = (B_ * OC_ * C_ * M_) / 4;   // 4,194,304
    for (int i = blockIdx.x * blockDim.x + threadIdx.x; i < n4;
         i += gridDim.x * blockDim.x) {
        const int m4 = i & 127;          // M/4 = 128
        const int c  = (i >> 7) & 63;
        const int o  = (i >> 13) & 31;
        const int b  = i >> 18;
        const float4 v = ((const float4*)snew)[(((b << 6) + c) << 7) + m4];
        const float w  = pw[o];
        const float bb = pb[o];
        float4 r;
        r.x = v.x * w + bb; r.y = v.y * w + bb;
        r.z = v.z * w + bb; r.w = v.w * w + bb;
        ((float4*)out)[i] = r;
    }
}

extern "C" void kernel_launch(void* const* d_in, const int* in_sizes, int n_in,
                              void* d_out, int out_size, void* d_ws, size_t ws_size,
                              hipStream_t stream)
{
    const float* x     = (const float*)d_in[0];
    const float* A     = (const float*)d_in[1];
    const float* phys  = (const float*)d_in[2];
    const float* kappa = (const float*)d_in[3];
    const float* alpha = (const float*)d_in[4];
    const float* w1    = (const float*)d_in[5];
    const float* b1    = (const float*)d_in[6];
    const float* w2    = (const float*)d_in[7];
    const float* b2    = (const float*)d_in[8];
    const float* pw    = (const float*)d_in[9];
    const float* pb    = (const float*)d_in[10];
    float* out = (float*)d_out;

    float* ws    = (float*)d_ws;
    float* s     = ws;                            // B*C*M
    float* snew  = ws + (size_t)B_ * C_ * M_;     // B*C*M
    float* rpart = ws + (size_t)2 * B_ * C_ * M_; // B*C*4 (16B-aligned)

    k1_mean<<<B_ * C_ * 4, 128, 0, stream>>>(x, s, rpart);
    k2_stream<<<512, 256, 0, stream>>>(A, phys, kappa, alpha, s, rpart,
                                       w1, b1, w2, b2, snew);
    k3_expand<<<2048, 256, 0, stream>>>(snew, pw, pb, out);
}

// Round 9
// 65.706 us; speedup vs baseline: 1.3408x; 1.1748x over previous
//
#include <hip/hip_runtime.h>
#include <math.h>

#define B_  16
#define F_  64
#define C_  64
#define M_  512
#define OC_ 32

typedef float vf4 __attribute__((ext_vector_type(4)));   // clang-native for nt stores

// ---------------------------------------------------------------------------
// k1: s[b,c,m] = mean_f x[b,f,c,m], m-split 4-ways for occupancy.
// (unchanged from R3 — best known)
// ---------------------------------------------------------------------------
__global__ __launch_bounds__(128, 6) void k1_mean(
    const float* __restrict__ x,
    float* __restrict__ s_out, float* __restrict__ rpart)
{
    const int gid = blockIdx.x;        // bc*4 + q
    const int q   = gid & 3;
    const int bc  = gid >> 2;
    const int b   = bc >> 6;
    const int c   = bc & 63;
    const int t   = threadIdx.x;
    const int tf  = t >> 5;            // 0..3 -> f chunk
    const int tm  = t & 31;            // float4 column within window
    const int m4  = (q << 5) + tm;     // global float4 index 0..127

    const size_t rowbase = ((size_t)b * F_ * C_ + c) * M_;   // + f*C*M
    float ax = 0.f, ay = 0.f, az = 0.f, aw = 0.f;
    #pragma unroll 8
    for (int j = 0; j < 16; ++j) {
        const int f = (tf << 4) + j;
        const float4 v = ((const float4*)(x + rowbase + (size_t)f * C_ * M_))[m4];
        ax += v.x; ay += v.y; az += v.z; aw += v.w;
    }

    __shared__ float4 red[4][32];
    red[tf][tm] = make_float4(ax, ay, az, aw);
    __syncthreads();

    if (tf == 0) {                     // lanes 0..31 of wave 0
        const float4 r1 = red[1][tm], r2 = red[2][tm], r3 = red[3][tm];
        const float inv_f = 1.0f / (float)F_;
        float4 sv;
        sv.x = (ax + r1.x + r2.x + r3.x) * inv_f;
        sv.y = (ay + r1.y + r2.y + r3.y) * inv_f;
        sv.z = (az + r1.z + r2.z + r3.z) * inv_f;
        sv.w = (aw + r1.w + r2.w + r3.w) * inv_f;
        ((float4*)(s_out + (size_t)bc * M_))[m4] = sv;

        float p = sv.x + sv.y + sv.z + sv.w;
        #pragma unroll
        for (int off = 16; off > 0; off >>= 1) p += __shfl_xor(p, off);
        if (t == 0) rpart[gid] = p;
    }
}

// ---------------------------------------------------------------------------
// k2 v3: per-(b,m) block of 256 threads (4 waves share one A tile).
// (unchanged from R3 — tied-best)
// ---------------------------------------------------------------------------
__global__ __launch_bounds__(256) void k2_laplace(
    const float* __restrict__ A, const float* __restrict__ phys,
    const float* __restrict__ kappa_p, const float* __restrict__ alpha_p,
    const float* __restrict__ s_in, const float* __restrict__ rpart,
    const float* __restrict__ w1, const float* __restrict__ b1,
    const float* __restrict__ w2, const float* __restrict__ b2,
    float* __restrict__ snew)
{
    __shared__ float Al[C_ * 65];
    __shared__ float sl[C_];
    __shared__ float redD[4 * C_];
    __shared__ float redA[4 * C_];

    const int bm = blockIdx.x;     // b*M + m
    const int b  = bm >> 9;
    const int m  = bm & 511;
    const int t  = threadIdx.x;    // 0..255
    const int c  = t & 63;
    const int q  = t >> 6;

    // r-MLP preamble: overlapped by the compiler with the A staging below
    float r = 0.f;
    if (t < 64) {
        const float4 rp = ((const float4*)rpart)[b * C_ + t];
        const float rin = (rp.x + rp.y + rp.z + rp.w) * (1.0f / (float)M_);
        r = b2[0];
        #pragma unroll
        for (int j = 0; j < 16; ++j) {
            float h = rin * w1[j] + b1[j];        // w1 is (16,1)
            h = (h > 0.f) ? h : (expf(h) - 1.f);  // ELU(alpha=1)
            r += h * w2[j];
        }
        sl[t] = s_in[((size_t)b * C_ + t) * M_ + m];
    }

    // stage A[b,m,:,:] (4096 f32) via coalesced float4 loads, pad stride 65
    const float4* Ap = (const float4*)(A + (size_t)bm * (C_ * C_));
    #pragma unroll
    for (int i = 0; i < 4; ++i) {
        const int idx = t + i * 256;       // float4 index 0..1023
        const float4 v = Ap[idx];
        const int row = idx >> 4;          // 16 float4 per row
        const int col = (idx & 15) << 2;
        float* dst = &Al[row * 65 + col];
        dst[0] = v.x; dst[1] = v.y; dst[2] = v.z; dst[3] = v.w;
    }
    __syncthreads();

    // quarter-reductions: q selects 16 of the 64 summation indices
    float dpart = 0.f, apart = 0.f;
    const int j0 = q << 4;
    #pragma unroll
    for (int j = 0; j < 16; ++j) {
        dpart += Al[c * 65 + (j0 + j)];              // row c (deg)
        apart += Al[(j0 + j) * 65 + c] * sl[j0 + j]; // col c (A^T s)
    }
    redD[(q << 6) + c] = dpart;
    redA[(q << 6) + c] = apart;
    __syncthreads();

    if (t < 64) {
        const float deg = redD[t] + redD[64 + t] + redD[128 + t] + redD[192 + t];
        const float As  = redA[t] + redA[64 + t] + redA[128 + t] + redA[192 + t];
        const float sval = sl[t];
        const float k    = log1pf(expf(kappa_p[0]));   // softplus
        const float Ls   = deg * sval - As;
        const float val  = sval - k * Ls
                         + (r + alpha_p[0] * phys[((size_t)b * C_ + t) * M_ + m]);
        snew[((size_t)b * C_ + t) * M_ + m] = val;
    }
}

// ---------------------------------------------------------------------------
// k3 v2: out[b,o,c,m] = s_new[b,c,m]*pw[o] + pb[o], NON-TEMPORAL stores.
// The 64 MB out-stream is write-once/never-read — nt keeps it from
// evicting x/A (256 MB combined) out of the Infinity Cache between
// graph replays. vf4 (clang ext_vector_type) because the builtin
// rejects HIP_vector_type.
// ---------------------------------------------------------------------------
__global__ __launch_bounds__(256) void k3_expand(
    const float* __restrict__ snew,
    const float* __restrict__ pw, const float* __restrict__ pb,
    float* __restrict__ out)
{
    const int n4 = (B_ * OC_ * C_ * M_) / 4;   // 4,194,304
    for (int i = blockIdx.x * blockDim.x + threadIdx.x; i < n4;
         i += gridDim.x * blockDim.x) {
        const int m4 = i & 127;          // M/4 = 128
        const int c  = (i >> 7) & 63;
        const int o  = (i >> 13) & 31;
        const int b  = i >> 18;
        const float4 v = ((const float4*)snew)[(((b << 6) + c) << 7) + m4];
        const float w  = pw[o];
        const float bb = pb[o];
        vf4 r;
        r.x = v.x * w + bb; r.y = v.y * w + bb;
        r.z = v.z * w + bb; r.w = v.w * w + bb;
        __builtin_nontemporal_store(r, ((vf4*)out) + i);
    }
}

extern "C" void kernel_launch(void* const* d_in, const int* in_sizes, int n_in,
                              void* d_out, int out_size, void* d_ws, size_t ws_size,
                              hipStream_t stream)
{
    const float* x     = (const float*)d_in[0];
    const float* A     = (const float*)d_in[1];
    const float* phys  = (const float*)d_in[2];
    const float* kappa = (const float*)d_in[3];
    const float* alpha = (const float*)d_in[4];
    const float* w1    = (const float*)d_in[5];
    const float* b1    = (const float*)d_in[6];
    const float* w2    = (const float*)d_in[7];
    const float* b2    = (const float*)d_in[8];
    const float* pw    = (const float*)d_in[9];
    const float* pb    = (const float*)d_in[10];
    float* out = (float*)d_out;

    float* ws    = (float*)d_ws;
    float* s     = ws;                            // B*C*M
    float* snew  = ws + (size_t)B_ * C_ * M_;     // B*C*M
    float* rpart = ws + (size_t)2 * B_ * C_ * M_; // B*C*4 (16B-aligned)

    k1_mean<<<B_ * C_ * 4, 128, 0, stream>>>(x, s, rpart);
    k2_laplace<<<B_ * M_, 256, 0, stream>>>(A, phys, kappa, alpha, s, rpart,
                                            w1, b1, w2, b2, snew);
    k3_expand<<<2048, 256, 0, stream>>>(snew, pw, pb, out);
}